// Round 2
// baseline (17116.554 us; speedup 1.0000x reference)
//
#include <hip/hip_runtime.h>
#include <math.h>

#define B_   64
#define T_   256
#define D_   512
#define H_   1024
#define G3_  3072
#define O_   64
#define NTOK (B_*T_)     // 16384
#define TC_  64          // timesteps per chunk
#define NCH_ 4           // chunks

// ---------------------------------------------------------------------------
// init: zero h slot 0 (fp64) and flags. grid 256 x 256.
// ---------------------------------------------------------------------------
__global__ __launch_bounds__(256) void init_ws(double* __restrict__ hs,
                                               int* __restrict__ flags)
{
  int idx = blockIdx.x*256 + threadIdx.x;   // 0..65535
  hs[idx] = 0.0;                            // slot 0 = [64][1024] doubles
  if (idx < 4096) flags[idx] = 0;
}

// ---------------------------------------------------------------------------
// Stage A (per chunk): gx[(tl*64+b)][g] = emb[x[b,t_base+tl]] . W_ih[g] + b_ih
// R3-proven 64x64 tile structure; fp32 LDS tiles (exact), fp64 FMA accum.
// Block = 64 timesteps of one batch x 64 gates. grid = 64*48 = 3072.
// ---------------------------------------------------------------------------
__global__ __launch_bounds__(256) void stage_a(
    const int* __restrict__ x, const float* __restrict__ emb,
    const float* __restrict__ W_ih, const float* __restrict__ b_ih,
    double* __restrict__ gx, int t_base)
{
  __shared__ float As[64][33];
  __shared__ float Bs[64][33];
  const int tid = threadIdx.x;
  const int b = blockIdx.x & 63, nBlk = blockIdx.x >> 6;
  const int g0 = nBlk*64;

  const int r = tid >> 2, c8 = tid & 3;     // r = t_local row / gate row
  const float* ap = emb  + (size_t)x[b*T_ + t_base + r]*D_ + c8*8;
  const float* bp = W_ih + (size_t)(g0 + r)*D_ + c8*8;
  const int tx = tid & 15, ty = tid >> 4;

  double acc[4][4];
  #pragma unroll
  for (int i = 0; i < 4; ++i)
    #pragma unroll
    for (int j = 0; j < 4; ++j) acc[i][j] = 0.0;

  float4 a0 = *(const float4*)(ap), a1 = *(const float4*)(ap + 4);
  float4 b0 = *(const float4*)(bp), b1 = *(const float4*)(bp + 4);

  for (int kb = 0; kb < 16; ++kb){
    __syncthreads();
    As[r][c8*8+0]=a0.x; As[r][c8*8+1]=a0.y; As[r][c8*8+2]=a0.z; As[r][c8*8+3]=a0.w;
    As[r][c8*8+4]=a1.x; As[r][c8*8+5]=a1.y; As[r][c8*8+6]=a1.z; As[r][c8*8+7]=a1.w;
    Bs[r][c8*8+0]=b0.x; Bs[r][c8*8+1]=b0.y; Bs[r][c8*8+2]=b0.z; Bs[r][c8*8+3]=b0.w;
    Bs[r][c8*8+4]=b1.x; Bs[r][c8*8+5]=b1.y; Bs[r][c8*8+6]=b1.z; Bs[r][c8*8+7]=b1.w;
    __syncthreads();
    if (kb < 15){
      a0 = *(const float4*)(ap + (kb+1)*32);  a1 = *(const float4*)(ap + (kb+1)*32 + 4);
      b0 = *(const float4*)(bp + (kb+1)*32);  b1 = *(const float4*)(bp + (kb+1)*32 + 4);
    }
    #pragma unroll
    for (int k = 0; k < 32; ++k){
      double av[4], bv[4];
      #pragma unroll
      for (int i = 0; i < 4; ++i) av[i] = (double)As[ty*4+i][k];
      #pragma unroll
      for (int j = 0; j < 4; ++j) bv[j] = (double)Bs[tx*4+j][k];
      #pragma unroll
      for (int i = 0; i < 4; ++i)
        #pragma unroll
        for (int j = 0; j < 4; ++j) acc[i][j] = fma(av[i], bv[j], acc[i][j]);
    }
  }

  double bi[4];
  #pragma unroll
  for (int j = 0; j < 4; ++j) bi[j] = (double)b_ih[g0 + tx*4 + j];
  #pragma unroll
  for (int i = 0; i < 4; ++i){
    int tl = ty*4 + i;
    size_t rowoff = ((size_t)tl*B_ + b)*G3_ + g0 + tx*4;
    #pragma unroll
    for (int j = 0; j < 4; ++j)
      gx[rowoff + j] = acc[i][j] + bi[j];
  }
}

// ---------------------------------------------------------------------------
// GRU recurrence (per chunk), fp64. Persistent: 256 WGs (1/CU), WG wg owns
// h cols wg*4..+3.
//
// R2 restructure (on top of R1's fence-free coherence scheme):
//  - 512 threads/WG (8 waves/CU = 2/SIMD): doubles latency-hiding TLP.
//    Thread = (bg 0..15 batch-group x j 0..3 col x ks 0..7 K-slice).
//  - 4 batches per weight read: 24 FMA per 3 ds_read_b128 -> LDS return
//    path (5.1 us/step/CU) now balances VALU (5.1 us) instead of 2x over.
//  - Wl stored as 96 slices [rr*8+ks][130 doubles]: slice stride 1040 B =
//    65 x 16B, 65 = 1 mod 8 -> the 32 distinct (j,ks) addresses of a wave
//    read cover the 8 bank-quads exactly 4x each (conflict-free optimal).
//  - K-reduce via shfl_xor(1,2,4); lanes ks<4 own batch bg*4+ks. Shadow
//    lanes (ks>=4) compute redundantly, never store; their gx/h loads are
//    same-address within the wave -> coalesced, no extra traffic.
//  - Coherence unchanged from R1 (validated): h(t+1) stores relaxed agent
//    (sc0 sc1 write-through to LLC), h(t) plain cached loads (slab fresh),
//    flag store relaxed after explicit vmcnt(0) drain + syncthreads.
// Flags carry GLOBAL step count (monotone across chunks). Bounded spin with
// WG-uniform abort (fail-soft).
// ---------------------------------------------------------------------------
__global__ __launch_bounds__(512, 1) void gru_rec(
    const float* __restrict__ W_hh, const float* __restrict__ b_hh,
    const double* __restrict__ gx, double* __restrict__ hs,
    int* __restrict__ flags, int t_base)
{
  __shared__ double Wl[96*130];              // 99,840 B; slice = (p*4+j)*8+ks
  __shared__ int abort_flag;
  const int tid = threadIdx.x, wg = blockIdx.x;
  const int i0 = wg*4;
  if (tid == 0) abort_flag = 0;

  for (int idx = tid; idx < 12*1024; idx += 512){
    int rr = idx >> 10, k = idx & 1023;      // rr = p*4+j
    int p = rr >> 2, j = rr & 3;
    int ksl = k >> 7, kl = k & 127;
    Wl[(rr*8 + ksl)*130 + kl] = (double)W_hh[(size_t)(p*H_ + i0 + j)*H_ + k];
  }

  const int ks = tid & 7;                    // K-slice 0..7 (128 doubles each)
  const int j  = (tid >> 3) & 3;             // column within WG
  const int bg = tid >> 5;                   // batch group 0..15 (4 batches)
  const int b0 = bg*4;
  const int b_out = b0 + (ks & 3);           // owned (or shadowed) batch
  const bool owner = (ks < 4);
  const int jj = i0 + j;
  const double bh0 = (double)b_hh[jj];
  const double bh1 = (double)b_hh[H_   + jj];
  const double bh2 = (double)b_hh[2*H_ + jj];
  const double2* w0p = (const double2*)&Wl[((0*4 + j)*8 + ks)*130];
  const double2* w1p = (const double2*)&Wl[((1*4 + j)*8 + ks)*130];
  const double2* w2p = (const double2*)&Wl[((2*4 + j)*8 + ks)*130];
  __syncthreads();

  // h_prev for this thread's (b_out, jj) cell; slot 0 seeded by init_ws
  // (chunk 0) or previous gru_rec launch (kernel-boundary coherent).
  double hprev = hs[(size_t)b_out*H_ + jj];

  for (int tt = 0; tt < TC_; ++tt){
    const int t = t_base + tt;

    // gx is pre-kernel data (stage_a): load BEFORE the spin, hide under it.
    const double* gp = gx + ((size_t)tt*B_ + b_out)*G3_ + jj;
    double gxr = gp[0];
    double gxz = gp[H_];
    double gxn = gp[2*H_];

    if (tid < 256){                          // waves 0-3 poll; 4-7 wait at bar
      int* fp = flags + tid*16;
      int gcnt = 0;
      while (__hip_atomic_load(fp, __ATOMIC_RELAXED, __HIP_MEMORY_SCOPE_AGENT) < t){
        __builtin_amdgcn_s_sleep(2);
        if (++gcnt > (1<<18)) { abort_flag = 1; break; }   // fail-soft
      }
    }
    __syncthreads();                         // also blocks hoist of h loads
    if (abort_flag) break;                   // WG-uniform: all threads bail

    const double2* h0p = (const double2*)(hs + ((size_t)tt*B_ + b0+0)*H_ + ks*128);
    const double2* h1p = (const double2*)(hs + ((size_t)tt*B_ + b0+1)*H_ + ks*128);
    const double2* h2p = (const double2*)(hs + ((size_t)tt*B_ + b0+2)*H_ + ks*128);
    const double2* h3p = (const double2*)(hs + ((size_t)tt*B_ + b0+3)*H_ + ks*128);

    double pr[3][4];
    #pragma unroll
    for (int g = 0; g < 3; ++g)
      #pragma unroll
      for (int i = 0; i < 4; ++i) pr[g][i] = 0.0;

    #pragma unroll 4
    for (int kk = 0; kk < 64; ++kk){
      double2 a[4];
      a[0] = h0p[kk]; a[1] = h1p[kk]; a[2] = h2p[kk]; a[3] = h3p[kk];
      double2 w0 = w0p[kk];
      double2 w1 = w1p[kk];
      double2 w2 = w2p[kk];
      #pragma unroll
      for (int i = 0; i < 4; ++i){
        pr[0][i] = fma(a[i].x, w0.x, pr[0][i]); pr[0][i] = fma(a[i].y, w0.y, pr[0][i]);
        pr[1][i] = fma(a[i].x, w1.x, pr[1][i]); pr[1][i] = fma(a[i].y, w1.y, pr[1][i]);
        pr[2][i] = fma(a[i].x, w2.x, pr[2][i]); pr[2][i] = fma(a[i].y, w2.y, pr[2][i]);
      }
    }

    // reduce over K-slices (lane bits 0-2 = ks)
    #pragma unroll
    for (int g = 0; g < 3; ++g)
      #pragma unroll
      for (int i = 0; i < 4; ++i){
        double v = pr[g][i];
        v += __shfl_xor(v, 1);
        v += __shfl_xor(v, 2);
        v += __shfl_xor(v, 4);
        pr[g][i] = v;
      }

    // select this lane's batch (index ks&3) - static register selects
    double sg[3];
    #pragma unroll
    for (int g = 0; g < 3; ++g){
      double sA = (ks & 1) ? pr[g][1] : pr[g][0];
      double sB = (ks & 1) ? pr[g][3] : pr[g][2];
      sg[g] = (ks & 2) ? sB : sA;
    }

    double rr_ = 1.0/(1.0 + exp(-(gxr + sg[0] + bh0)));
    double zz  = 1.0/(1.0 + exp(-(gxz + sg[1] + bh1)));
    double nn  = tanh(gxn + rr_*(sg[2] + bh2));
    double hnew = (1.0 - zz)*nn + zz*hprev;
    hprev = hnew;

    if (owner){
      // LLC-direct (sc0 sc1) stores: agent-visible without release fence.
      __hip_atomic_store(&hs[((size_t)(tt+1)*B_ + b_out)*H_ + jj], hnew,
                         __ATOMIC_RELAXED, __HIP_MEMORY_SCOPE_AGENT);
      if (tt == TC_-1)
        __hip_atomic_store(&hs[(size_t)b_out*H_ + jj], hnew,
                           __ATOMIC_RELAXED, __HIP_MEMORY_SCOPE_AGENT);
    }

    asm volatile("s_waitcnt vmcnt(0)" ::: "memory");  // stores acked at LLC
    __syncthreads();                                  // all 8 waves drained
    if (tid == 0)
      __hip_atomic_store(flags + wg*16, t+1, __ATOMIC_RELAXED, __HIP_MEMORY_SCOPE_AGENT);
  }
}

// ---------------------------------------------------------------------------
// FC + sigmoid + labels (per chunk). fp64 accumulation.
// Labels emulate an fp32 sigmoid+threshold: pf = 1/(1+exp32(-logit32)),
// label = pf > 0.5f. (exp32 emulated as correctly-rounded via fp64 exp.)
// Block = batch b: 64 timesteps x 64 outputs, K=1024. grid 64.
// ---------------------------------------------------------------------------
__global__ __launch_bounds__(256) void fc_out(
    const double* __restrict__ hs, const float* __restrict__ W_fc,
    const float* __restrict__ b_fc, float* __restrict__ out, int t_base)
{
  __shared__ double Ah[64][34];
  __shared__ double Bw[64][34];
  const int tid = threadIdx.x;
  const int b = blockIdx.x;
  const int r = tid >> 2, c8 = tid & 3;
  const double* ap = hs   + ((size_t)(r+1)*B_ + b)*H_ + c8*8;   // slot = tl+1
  const float*  bp = W_fc + (size_t)r*H_ + c8*8;
  const int tx = tid & 15, ty = tid >> 4;

  double acc[4][4];
  #pragma unroll
  for (int i = 0; i < 4; ++i)
    #pragma unroll
    for (int j = 0; j < 4; ++j) acc[i][j] = 0.0;

  double ar0[8]; float br0[8];
  #pragma unroll
  for (int e = 0; e < 8; ++e){ ar0[e] = ap[e]; br0[e] = bp[e]; }

  for (int kb = 0; kb < 32; ++kb){
    __syncthreads();
    #pragma unroll
    for (int e = 0; e < 8; ++e){
      Ah[r][c8*8+e] = ar0[e];
      Bw[r][c8*8+e] = (double)br0[e];
    }
    __syncthreads();
    if (kb < 31){
      #pragma unroll
      for (int e = 0; e < 8; ++e){
        ar0[e] = ap[(kb+1)*32 + e];
        br0[e] = bp[(kb+1)*32 + e];
      }
    }
    #pragma unroll
    for (int k = 0; k < 32; ++k){
      double av[4], bv[4];
      #pragma unroll
      for (int i = 0; i < 4; ++i) av[i] = Ah[ty*4+i][k];
      #pragma unroll
      for (int j = 0; j < 4; ++j) bv[j] = Bw[tx*4+j][k];
      #pragma unroll
      for (int i = 0; i < 4; ++i)
        #pragma unroll
        for (int j = 0; j < 4; ++j) acc[i][j] = fma(av[i], bv[j], acc[i][j]);
    }
  }

  double bi[4];
  #pragma unroll
  for (int j = 0; j < 4; ++j) bi[j] = (double)b_fc[tx*4 + j];
  #pragma unroll
  for (int i = 0; i < 4; ++i){
    int tl = ty*4 + i;
    size_t tok = (size_t)b*T_ + t_base + tl;
    float4 pr, lb;
    float* prp = (float*)&pr; float* lbp = (float*)&lb;
    #pragma unroll
    for (int j = 0; j < 4; ++j){
      double logit = acc[i][j] + bi[j];
      prp[j] = (float)(1.0/(1.0 + exp(-logit)));
      // fp32-sigmoid-emulated label rule:
      float lf = (float)logit;                    // fp32 logit
      float ef = (float)exp(-(double)lf);         // correctly-rounded fp32 exp
      float pf = 1.0f / (1.0f + ef);              // fp32 ops thereafter
      lbp[j] = (pf > 0.5f) ? 1.0f : 0.0f;
    }
    *(float4*)&out[tok*O_ + tx*4] = pr;
    *(float4*)&out[(size_t)NTOK*O_ + tok*O_ + tx*4] = lb;
  }
}

// ---------------------------------------------------------------------------
extern "C" void kernel_launch(void* const* d_in, const int* in_sizes, int n_in,
                              void* d_out, int out_size, void* d_ws, size_t ws_size,
                              hipStream_t stream) {
  const int*   x    = (const int*)  d_in[0];
  const float* emb  = (const float*)d_in[1];
  const float* W_ih = (const float*)d_in[2];
  const float* W_hh = (const float*)d_in[3];
  const float* b_ih = (const float*)d_in[4];
  const float* b_hh = (const float*)d_in[5];
  const float* W_fc = (const float*)d_in[6];
  const float* b_fc = (const float*)d_in[7];
  float* out = (float*)d_out;
  char* ws = (char*)d_ws;

  // ws layout (bytes) — total 134,758,400
  double* gx    = (double*)(ws);                 // 64*64*3072*8  = 100,663,296
  double* hs    = (double*)(ws + 100663296);     // 65*64*1024*8  =  34,078,720
  int*    flags = (int*)   (ws + 134742016);     // 16,384

  hipLaunchKernelGGL(init_ws, dim3(256), dim3(256), 0, stream, hs, flags);
  for (int c = 0; c < NCH_; ++c){
    int t_base = c*TC_;
    hipLaunchKernelGGL(stage_a, dim3(3072), dim3(256), 0, stream,
                       x, emb, W_ih, b_ih, gx, t_base);
    hipLaunchKernelGGL(gru_rec, dim3(256), dim3(512), 0, stream,
                       W_hh, b_hh, gx, hs, flags, t_base);
    hipLaunchKernelGGL(fc_out, dim3(64), dim3(256), 0, stream,
                       hs, W_fc, b_fc, out, t_base);
  }
}

// Round 4
// 10011.036 us; speedup vs baseline: 1.7098x; 1.7098x over previous
//
#include <hip/hip_runtime.h>
#include <math.h>

#define B_   64
#define T_   256
#define D_   512
#define H_   1024
#define G3_  3072
#define O_   64
#define NTOK (B_*T_)     // 16384
#define TC_  64          // timesteps per chunk
#define NCH_ 4           // chunks

// ---------------------------------------------------------------------------
// init: zero h slot 0 (fp64) and flags. grid 256 x 256.
// ---------------------------------------------------------------------------
__global__ __launch_bounds__(256) void init_ws(double* __restrict__ hs,
                                               int* __restrict__ flags)
{
  int idx = blockIdx.x*256 + threadIdx.x;   // 0..65535
  hs[idx] = 0.0;                            // slot 0 = [64][1024] doubles
  if (idx < 4096) flags[idx] = 0;
}

// ---------------------------------------------------------------------------
// Stage A (per chunk): gx[(tl*64+b)][g] = emb[x[b,t_base+tl]] . W_ih[g] + b_ih
// R3-proven 64x64 tile structure; fp32 LDS tiles (exact), fp64 FMA accum.
// Block = 64 timesteps of one batch x 64 gates. grid = 64*48 = 3072.
// ---------------------------------------------------------------------------
__global__ __launch_bounds__(256) void stage_a(
    const int* __restrict__ x, const float* __restrict__ emb,
    const float* __restrict__ W_ih, const float* __restrict__ b_ih,
    double* __restrict__ gx, int t_base)
{
  __shared__ float As[64][33];
  __shared__ float Bs[64][33];
  const int tid = threadIdx.x;
  const int b = blockIdx.x & 63, nBlk = blockIdx.x >> 6;
  const int g0 = nBlk*64;

  const int r = tid >> 2, c8 = tid & 3;     // r = t_local row / gate row
  const float* ap = emb  + (size_t)x[b*T_ + t_base + r]*D_ + c8*8;
  const float* bp = W_ih + (size_t)(g0 + r)*D_ + c8*8;
  const int tx = tid & 15, ty = tid >> 4;

  double acc[4][4];
  #pragma unroll
  for (int i = 0; i < 4; ++i)
    #pragma unroll
    for (int j = 0; j < 4; ++j) acc[i][j] = 0.0;

  float4 a0 = *(const float4*)(ap), a1 = *(const float4*)(ap + 4);
  float4 b0 = *(const float4*)(bp), b1 = *(const float4*)(bp + 4);

  for (int kb = 0; kb < 16; ++kb){
    __syncthreads();
    As[r][c8*8+0]=a0.x; As[r][c8*8+1]=a0.y; As[r][c8*8+2]=a0.z; As[r][c8*8+3]=a0.w;
    As[r][c8*8+4]=a1.x; As[r][c8*8+5]=a1.y; As[r][c8*8+6]=a1.z; As[r][c8*8+7]=a1.w;
    Bs[r][c8*8+0]=b0.x; Bs[r][c8*8+1]=b0.y; Bs[r][c8*8+2]=b0.z; Bs[r][c8*8+3]=b0.w;
    Bs[r][c8*8+4]=b1.x; Bs[r][c8*8+5]=b1.y; Bs[r][c8*8+6]=b1.z; Bs[r][c8*8+7]=b1.w;
    __syncthreads();
    if (kb < 15){
      a0 = *(const float4*)(ap + (kb+1)*32);  a1 = *(const float4*)(ap + (kb+1)*32 + 4);
      b0 = *(const float4*)(bp + (kb+1)*32);  b1 = *(const float4*)(bp + (kb+1)*32 + 4);
    }
    #pragma unroll
    for (int k = 0; k < 32; ++k){
      double av[4], bv[4];
      #pragma unroll
      for (int i = 0; i < 4; ++i) av[i] = (double)As[ty*4+i][k];
      #pragma unroll
      for (int j = 0; j < 4; ++j) bv[j] = (double)Bs[tx*4+j][k];
      #pragma unroll
      for (int i = 0; i < 4; ++i)
        #pragma unroll
        for (int j = 0; j < 4; ++j) acc[i][j] = fma(av[i], bv[j], acc[i][j]);
    }
  }

  double bi[4];
  #pragma unroll
  for (int j = 0; j < 4; ++j) bi[j] = (double)b_ih[g0 + tx*4 + j];
  #pragma unroll
  for (int i = 0; i < 4; ++i){
    int tl = ty*4 + i;
    size_t rowoff = ((size_t)tl*B_ + b)*G3_ + g0 + tx*4;
    #pragma unroll
    for (int j = 0; j < 4; ++j)
      gx[rowoff + j] = acc[i][j] + bi[j];
  }
}

// ---------------------------------------------------------------------------
// GRU recurrence (per chunk), fp64. Persistent: 256 WGs (1/CU), WG wg owns
// h cols wg*4..+3. Numeric core = R1-validated structure (256 thr, bq/j/half
// map, unroll-8 dot loop, Wl[2][12][514] conflict-free LDS, fence-free LLC
// coherence).
//
// R4 sync (contention-safe 2-level tree + mirror broadcast):
//  - arrival: tid0 fetch_add(group[wg&7]) (8 lines); 32nd arrival of a group
//    fetch_adds master; 8th group completion (om == 8(t+1)-1) => final closer
//    stores (t+1) to 8 MIRROR lines.
//  - poll: tid0 only, on mirror[wg&7] (32 pollers/line, s_sleep backoff
//    2->32: ~0.03 req/cyc/line, far under same-line LLC service rate).
//    Rest of WG waits at __syncthreads.
//  - visibility: h stores (relaxed agent, sc0 sc1 write-through to LLC)
//    -> vmcnt(0) drain -> barrier -> group add -> master add -> mirror store.
//    Poller sees mirror >= t => all h stores of step t-1 at LLC => fresh-slab
//    cached loads see them.
//  - fail-soft: spin bound 2^13 (~8 ms) then WG-uniform abort that BREAKS the
//    loop => a livelocked dispatch exits in ~10 ms (no container timeout).
// Flags carry GLOBAL step count (monotone across chunks; replay-safe via
// init_ws re-zero).
// ---------------------------------------------------------------------------
__global__ __launch_bounds__(256, 1) void gru_rec(
    const float* __restrict__ W_hh, const float* __restrict__ b_hh,
    const double* __restrict__ gx, double* __restrict__ hs,
    int* __restrict__ flags, int t_base)
{
  __shared__ double Wl[2*12*514];            // [half][rr][514]; rr: 0-3=r,4-7=z,8-11=n
  __shared__ int abort_flag;
  const int tid = threadIdx.x, wg = blockIdx.x;
  const int i0 = wg*4;
  if (tid == 0) abort_flag = 0;

  for (int it = tid; it < 12*1024; it += 256){
    int rr = it >> 10, k = it & 1023;
    int p = rr >> 2, j = rr & 3;
    int hf = k >> 9, kl = k & 511;
    Wl[(hf*12 + rr)*514 + kl] = (double)W_hh[(size_t)(p*H_ + i0 + j)*H_ + k];
  }

  const int bq = tid >> 3, j = (tid >> 1) & 3, half = tid & 1;
  const int b_out = bq*2 + half;
  const int jj = i0 + j;
  const double bh0 = (double)b_hh[jj];
  const double bh1 = (double)b_hh[H_   + jj];
  const double bh2 = (double)b_hh[2*H_ + jj];
  const double2* w0p = (const double2*)&Wl[(half*12 + 0*4 + j)*514];
  const double2* w1p = (const double2*)&Wl[(half*12 + 1*4 + j)*514];
  const double2* w2p = (const double2*)&Wl[(half*12 + 2*4 + j)*514];
  __syncthreads();

  // h_prev for this thread's own (b_out, jj) cell; slot 0 seeded by
  // init_ws (chunk 0) or previous gru_rec launch (kernel-boundary coherent).
  double hprev = hs[(size_t)b_out*H_ + jj];

  for (int tt = 0; tt < TC_; ++tt){
    const int t = t_base + tt;

    // gx is pre-kernel data (stage_a): load BEFORE the spin, hide under it.
    const double* gp = gx + ((size_t)tt*B_ + b_out)*G3_ + jj;
    double gxr = gp[0];
    double gxz = gp[H_];
    double gxn = gp[2*H_];

    if (tid == 0){                           // single poller per WG, group mirror
      int* mp = &flags[256 + 16*(wg & 7)];   // mirror == steps complete
      int gcnt = 0;
      while (__hip_atomic_load(mp, __ATOMIC_RELAXED, __HIP_MEMORY_SCOPE_AGENT) < t){
        if (gcnt < 32) __builtin_amdgcn_s_sleep(2);
        else           __builtin_amdgcn_s_sleep(32);
        if (++gcnt > (1<<13)) { abort_flag = 1; break; }   // fail-soft, fast
      }
    }
    __syncthreads();                         // releases WG; blocks h-load hoist
    if (abort_flag) break;                   // WG-uniform: all threads bail

    const double2* h0 = (const double2*)(hs + ((size_t)tt*B_ + bq*2    )*H_ + half*512);
    const double2* h1 = (const double2*)(hs + ((size_t)tt*B_ + bq*2 + 1)*H_ + half*512);

    double pr00=0.0, pr10=0.0, pr20=0.0, pr01=0.0, pr11=0.0, pr21=0.0;
    #pragma unroll 8
    for (int kk = 0; kk < 256; ++kk){
      double2 a0 = h0[kk];
      double2 a1 = h1[kk];
      double2 w0 = w0p[kk];
      double2 w1 = w1p[kk];
      double2 w2 = w2p[kk];
      pr00 = fma(a0.x, w0.x, pr00); pr00 = fma(a0.y, w0.y, pr00);
      pr10 = fma(a0.x, w1.x, pr10); pr10 = fma(a0.y, w1.y, pr10);
      pr20 = fma(a0.x, w2.x, pr20); pr20 = fma(a0.y, w2.y, pr20);
      pr01 = fma(a1.x, w0.x, pr01); pr01 = fma(a1.y, w0.y, pr01);
      pr11 = fma(a1.x, w1.x, pr11); pr11 = fma(a1.y, w1.y, pr11);
      pr21 = fma(a1.x, w2.x, pr21); pr21 = fma(a1.y, w2.y, pr21);
    }
    double s00 = pr00 + __shfl_xor(pr00, 1);
    double s01 = pr01 + __shfl_xor(pr01, 1);
    double s10 = pr10 + __shfl_xor(pr10, 1);
    double s11 = pr11 + __shfl_xor(pr11, 1);
    double s20 = pr20 + __shfl_xor(pr20, 1);
    double s21 = pr21 + __shfl_xor(pr21, 1);
    double ar = half ? s01 : s00;
    double az = half ? s11 : s10;
    double an = half ? s21 : s20;

    double rr_ = 1.0/(1.0 + exp(-(gxr + ar + bh0)));
    double zz  = 1.0/(1.0 + exp(-(gxz + az + bh1)));
    double nn  = tanh(gxn + rr_*(an + bh2));
    double hnew = (1.0 - zz)*nn + zz*hprev;
    hprev = hnew;

    // LLC-direct (sc0 sc1) stores: agent-visible without any release fence.
    __hip_atomic_store(&hs[((size_t)(tt+1)*B_ + b_out)*H_ + jj], hnew,
                       __ATOMIC_RELAXED, __HIP_MEMORY_SCOPE_AGENT);
    if (tt == TC_-1)
      __hip_atomic_store(&hs[(size_t)b_out*H_ + jj], hnew,
                         __ATOMIC_RELAXED, __HIP_MEMORY_SCOPE_AGENT);

    asm volatile("s_waitcnt vmcnt(0)" ::: "memory");  // stores acked at LLC
    __syncthreads();                                  // all 4 waves drained
    if (tid == 0){
      // 2-level arrival: group line, then master, then mirror broadcast.
      int old = __hip_atomic_fetch_add(&flags[16 + 16*(wg & 7)], 1,
                                       __ATOMIC_RELAXED, __HIP_MEMORY_SCOPE_AGENT);
      if (old == 32*(t+1) - 1){
        int om = __hip_atomic_fetch_add(&flags[0], 1,
                                        __ATOMIC_RELAXED, __HIP_MEMORY_SCOPE_AGENT);
        if (om == 8*(t+1) - 1){
          #pragma unroll
          for (int g = 0; g < 8; ++g)
            __hip_atomic_store(&flags[256 + 16*g], t+1,
                               __ATOMIC_RELAXED, __HIP_MEMORY_SCOPE_AGENT);
        }
      }
    }
  }
}

// ---------------------------------------------------------------------------
// FC + sigmoid + labels (per chunk). fp64 accumulation.
// Labels emulate an fp32 sigmoid+threshold: pf = 1/(1+exp32(-logit32)),
// label = pf > 0.5f. (exp32 emulated as correctly-rounded via fp64 exp.)
// Block = batch b: 64 timesteps x 64 outputs, K=1024. grid 64.
// ---------------------------------------------------------------------------
__global__ __launch_bounds__(256) void fc_out(
    const double* __restrict__ hs, const float* __restrict__ W_fc,
    const float* __restrict__ b_fc, float* __restrict__ out, int t_base)
{
  __shared__ double Ah[64][34];
  __shared__ double Bw[64][34];
  const int tid = threadIdx.x;
  const int b = blockIdx.x;
  const int r = tid >> 2, c8 = tid & 3;
  const double* ap = hs   + ((size_t)(r+1)*B_ + b)*H_ + c8*8;   // slot = tl+1
  const float*  bp = W_fc + (size_t)r*H_ + c8*8;
  const int tx = tid & 15, ty = tid >> 4;

  double acc[4][4];
  #pragma unroll
  for (int i = 0; i < 4; ++i)
    #pragma unroll
    for (int j = 0; j < 4; ++j) acc[i][j] = 0.0;

  double ar0[8]; float br0[8];
  #pragma unroll
  for (int e = 0; e < 8; ++e){ ar0[e] = ap[e]; br0[e] = bp[e]; }

  for (int kb = 0; kb < 32; ++kb){
    __syncthreads();
    #pragma unroll
    for (int e = 0; e < 8; ++e){
      Ah[r][c8*8+e] = ar0[e];
      Bw[r][c8*8+e] = (double)br0[e];
    }
    __syncthreads();
    if (kb < 31){
      #pragma unroll
      for (int e = 0; e < 8; ++e){
        ar0[e] = ap[(kb+1)*32 + e];
        br0[e] = bp[(kb+1)*32 + e];
      }
    }
    #pragma unroll
    for (int k = 0; k < 32; ++k){
      double av[4], bv[4];
      #pragma unroll
      for (int i = 0; i < 4; ++i) av[i] = Ah[ty*4+i][k];
      #pragma unroll
      for (int j = 0; j < 4; ++j) bv[j] = Bw[tx*4+j][k];
      #pragma unroll
      for (int i = 0; i < 4; ++i)
        #pragma unroll
        for (int j = 0; j < 4; ++j) acc[i][j] = fma(av[i], bv[j], acc[i][j]);
    }
  }

  double bi[4];
  #pragma unroll
  for (int j = 0; j < 4; ++j) bi[j] = (double)b_fc[tx*4 + j];
  #pragma unroll
  for (int i = 0; i < 4; ++i){
    int tl = ty*4 + i;
    size_t tok = (size_t)b*T_ + t_base + tl;
    float4 pr, lb;
    float* prp = (float*)&pr; float* lbp = (float*)&lb;
    #pragma unroll
    for (int j = 0; j < 4; ++j){
      double logit = acc[i][j] + bi[j];
      prp[j] = (float)(1.0/(1.0 + exp(-logit)));
      // fp32-sigmoid-emulated label rule:
      float lf = (float)logit;                    // fp32 logit
      float ef = (float)exp(-(double)lf);         // correctly-rounded fp32 exp
      float pf = 1.0f / (1.0f + ef);              // fp32 ops thereafter
      lbp[j] = (pf > 0.5f) ? 1.0f : 0.0f;
    }
    *(float4*)&out[tok*O_ + tx*4] = pr;
    *(float4*)&out[(size_t)NTOK*O_ + tok*O_ + tx*4] = lb;
  }
}

// ---------------------------------------------------------------------------
extern "C" void kernel_launch(void* const* d_in, const int* in_sizes, int n_in,
                              void* d_out, int out_size, void* d_ws, size_t ws_size,
                              hipStream_t stream) {
  const int*   x    = (const int*)  d_in[0];
  const float* emb  = (const float*)d_in[1];
  const float* W_ih = (const float*)d_in[2];
  const float* W_hh = (const float*)d_in[3];
  const float* b_ih = (const float*)d_in[4];
  const float* b_hh = (const float*)d_in[5];
  const float* W_fc = (const float*)d_in[6];
  const float* b_fc = (const float*)d_in[7];
  float* out = (float*)d_out;
  char* ws = (char*)d_ws;

  // ws layout (bytes) — total 134,758,400
  double* gx    = (double*)(ws);                 // 64*64*3072*8  = 100,663,296
  double* hs    = (double*)(ws + 100663296);     // 65*64*1024*8  =  34,078,720
  int*    flags = (int*)   (ws + 134742016);     // [0]=master, 16..128=groups, 256..368=mirrors
  hipLaunchKernelGGL(init_ws, dim3(256), dim3(256), 0, stream, hs, flags);
  for (int c = 0; c < NCH_; ++c){
    int t_base = c*TC_;
    hipLaunchKernelGGL(stage_a, dim3(3072), dim3(256), 0, stream,
                       x, emb, W_ih, b_ih, gx, t_base);
    hipLaunchKernelGGL(gru_rec, dim3(256), dim3(256), 0, stream,
                       W_hh, b_hh, gx, hs, flags, t_base);
    hipLaunchKernelGGL(fc_out, dim3(64), dim3(256), 0, stream,
                       hs, W_fc, b_fc, out, t_base);
  }
}